// Round 1
// baseline (2867.730 us; speedup 1.0000x reference)
//
#include <hip/hip_runtime.h>

// ---------------------------------------------------------------------------
// SLAYER-style spiking CNN forward pass, MI355X.
//
// psp (SRM alpha kernel) as double-exponential IIR cascade:
//   eps[k] = (e/tau) * k * a^k,  a = exp(-1/tau)
//   g1[t] = x[t] + a*g1[t-1];  g2[t] = g1[t] + a*g2[t-1];  u[t] = (e/tau)*(g2-g1)
// All accumulation in f64 for exact spike-pattern match vs numpy reference.
// ---------------------------------------------------------------------------

namespace {
constexpr int B = 32, T = 100;
constexpr double A1 = 0.90483741803595957;  // exp(-1/10)
constexpr double CE = 0.27182818284590452;  // e/10

// workspace byte offsets
constexpr size_t OFF_X0 = 0;                                   // u8 [B][T][784]
constexpr size_t OFF_S1 = OFF_X0 + (size_t)B * T * 784;        // u8 [B][T][16][784]
constexpr size_t OFF_S2 = OFF_S1 + (size_t)B * T * 16 * 784;   // u8 [B][T][16][196]
constexpr size_t OFF_S3 = OFF_S2 + (size_t)B * T * 16 * 196;   // u8 [B][T][32][196]
constexpr size_t OFF_S4 = OFF_S3 + (size_t)B * T * 32 * 196;   // u8 [B][T][1568]
constexpr size_t OFF_D5 = OFF_S4 + (size_t)B * T * 1568;       // f64 [B*T][410]
constexpr size_t OFF_S5 = OFF_D5 + (size_t)B * T * 410 * 8;    // u8 [B*T][410]
constexpr size_t OFF_D6 = OFF_S5 + (size_t)B * T * 410;        // f64 [B*T][10]
constexpr size_t OFF_WT = OFF_D6 + (size_t)B * T * 10 * 8;     // f32 [1568][410]
}  // namespace

// Stage 0: rate encode.  x0[b][t][hw] = (rand_u[b,hw,t] < img[b,hw])
__global__ void k_encode(const float* __restrict__ img, const float* __restrict__ ru,
                         unsigned char* __restrict__ x0) {
  int i = blockIdx.x * 256 + threadIdx.x;
  if (i >= B * T * 784) return;
  int hw = i % 784;
  int t = (i / 784) % T;
  int b = i / (784 * T);
  x0[i] = (ru[(size_t)b * 78400 + hw * 100 + t] < img[b * 784 + hw]) ? 1 : 0;
}

// Stage 1: conv1 (1->16, 5x5, pad 2) + psp + spike.  One thread per (b,o,y,x).
__global__ __launch_bounds__(256) void k_conv1(const unsigned char* __restrict__ x0,
                                               const float* __restrict__ w1,
                                               unsigned char* __restrict__ s1) {
  int tid = blockIdx.x * 256 + threadIdx.x;
  if (tid >= B * 16 * 784) return;
  int x = tid % 28, y = (tid / 28) % 28, o = (tid / 784) % 16, b = tid / (784 * 16);
  double w[25];
#pragma unroll
  for (int k = 0; k < 25; k++) w[k] = (double)w1[o * 25 + k];
  double g1 = 0.0, g2 = 0.0;
  const unsigned char* xb = x0 + (size_t)b * T * 784;
  for (int t = 0; t < T; t++) {
    const unsigned char* xs = xb + (size_t)t * 784;
    double s = 0.0;
#pragma unroll
    for (int dy = 0; dy < 5; dy++) {
      int iy = y + dy - 2;
      if ((unsigned)iy >= 28u) continue;
      const unsigned char* row = xs + iy * 28;
#pragma unroll
      for (int dx = 0; dx < 5; dx++) {
        int ix = x + dx - 2;
        if ((unsigned)ix >= 28u) continue;
        s += w[dy * 5 + dx] * (double)row[ix];
      }
    }
    g1 = s + A1 * g1;
    g2 = g1 + A1 * g2;
    double u = CE * (g2 - g1);
    s1[((size_t)(b * T + t) * 16 + o) * 784 + y * 28 + x] = (u >= 1.0) ? 1 : 0;
  }
}

// Pool (2x2 sum * 1.1) + psp + spike.  One thread per (b,c,y,x).
template <int C, int HO, int WO>
__global__ __launch_bounds__(256) void k_pool(const unsigned char* __restrict__ in,
                                              unsigned char* __restrict__ out) {
  int tid = blockIdx.x * 256 + threadIdx.x;
  if (tid >= B * C * HO * WO) return;
  int x = tid % WO, y = (tid / WO) % HO, c = (tid / (WO * HO)) % C, b = tid / (WO * HO * C);
  double g1 = 0.0, g2 = 0.0;
  for (int t = 0; t < T; t++) {
    const unsigned char* p =
        in + ((size_t)(b * T + t) * C + c) * (4 * HO * WO) + (2 * y) * (2 * WO) + 2 * x;
    int ksum = (int)p[0] + (int)p[1] + (int)p[2 * WO] + (int)p[2 * WO + 1];
    double s = 1.1 * (double)ksum;
    g1 = s + A1 * g1;
    g2 = g1 + A1 * g2;
    double u = CE * (g2 - g1);
    out[((size_t)(b * T + t) * C + c) * (HO * WO) + y * WO + x] = (u >= 1.0) ? 1 : 0;
  }
}

// Stage 3: conv2 (16->32, 5x5, pad 2) + psp + spike.
// Block = one (b,o); threads 0..195 are spatial positions; input slice + weights in LDS.
__global__ __launch_bounds__(256) void k_conv2(const unsigned char* __restrict__ s2,
                                               const float* __restrict__ w2,
                                               unsigned char* __restrict__ s3) {
  __shared__ float wl[400];
  __shared__ unsigned int slw[784];  // 3136 bytes
  unsigned char* sl = (unsigned char*)slw;
  int o = blockIdx.x % 32, b = blockIdx.x / 32;
  int tid = threadIdx.x;
  for (int k = tid; k < 400; k += 256) wl[k] = w2[o * 400 + k];
  int x = tid % 14, y = tid / 14;
  bool act = tid < 196;
  double g1 = 0.0, g2 = 0.0;
  for (int t = 0; t < T; t++) {
    __syncthreads();  // previous-iteration readers done (also fences wl on t==0)
    const unsigned int* src = (const unsigned int*)(s2 + (size_t)(b * T + t) * 3136);
    for (int k = tid; k < 784; k += 256) slw[k] = src[k];
    __syncthreads();
    if (act) {
      double s = 0.0;
      for (int ci = 0; ci < 16; ci++) {
        const unsigned char* sc = sl + ci * 196;
        const float* wc = wl + ci * 25;
#pragma unroll
        for (int dy = 0; dy < 5; dy++) {
          int iy = y + dy - 2;
          if ((unsigned)iy >= 14u) continue;
#pragma unroll
          for (int dx = 0; dx < 5; dx++) {
            int ix = x + dx - 2;
            if ((unsigned)ix >= 14u) continue;
            s += (double)wc[dy * 5 + dx] * (double)sc[iy * 14 + ix];
          }
        }
      }
      g1 = s + A1 * g1;
      g2 = g1 + A1 * g2;
      double u = CE * (g2 - g1);
      s3[((size_t)(b * T + t) * 32 + o) * 196 + y * 14 + x] = (u >= 1.0) ? 1 : 0;
    }
  }
}

// Transpose wf1 [410][1568] -> wt [1568][410] for coalesced dense1 reads.
__global__ void k_transpose(const float* __restrict__ wf1, float* __restrict__ wt) {
  int i = blockIdx.x * 256 + threadIdx.x;
  if (i >= 410 * 1568) return;
  int col = i % 410, row = i / 410;
  wt[i] = wf1[col * 1568 + row];
}

// Stage 5a: dense1 matmul.  Block = 64 o-lanes x 4 bt-groups; 16 (b,t) columns in LDS.
__global__ __launch_bounds__(256) void k_dense1(const unsigned char* __restrict__ s4,
                                                const float* __restrict__ wt,
                                                double* __restrict__ d5) {
  __shared__ unsigned char sl[16 * 1568];  // 25088 B
  int obase = blockIdx.x * 64;   // gridDim.x = 7
  int btbase = blockIdx.y * 16;  // gridDim.y = 200
  int tid = threadIdx.x;
  int olane = tid % 64, bts = tid / 64;
  const unsigned int* src = (const unsigned int*)(s4 + (size_t)btbase * 1568);
  unsigned int* dst = (unsigned int*)sl;
  for (int k = tid; k < 6272; k += 256) dst[k] = src[k];
  __syncthreads();
  int o = obase + olane;
  bool store = o < 410;
  int osafe = store ? o : 409;
  double a0 = 0.0, a1 = 0.0, a2 = 0.0, a3 = 0.0;
  const unsigned char* c0 = sl + (bts * 4 + 0) * 1568;
  const unsigned char* c1 = sl + (bts * 4 + 1) * 1568;
  const unsigned char* c2 = sl + (bts * 4 + 2) * 1568;
  const unsigned char* c3 = sl + (bts * 4 + 3) * 1568;
  for (int i = 0; i < 1568; i++) {
    double wv = (double)wt[(size_t)i * 410 + osafe];
    a0 += wv * (double)c0[i];
    a1 += wv * (double)c1[i];
    a2 += wv * (double)c2[i];
    a3 += wv * (double)c3[i];
  }
  if (store) {
    d5[(size_t)(btbase + bts * 4 + 0) * 410 + o] = a0;
    d5[(size_t)(btbase + bts * 4 + 1) * 410 + o] = a1;
    d5[(size_t)(btbase + bts * 4 + 2) * 410 + o] = a2;
    d5[(size_t)(btbase + bts * 4 + 3) * 410 + o] = a3;
  }
}

// Stage 5b: psp + spike over dense1 output.  One thread per (b,o).
__global__ void k_psp5(const double* __restrict__ d5, unsigned char* __restrict__ s5) {
  int tid = blockIdx.x * 256 + threadIdx.x;
  if (tid >= B * 410) return;
  int o = tid % 410, b = tid / 410;
  double g1 = 0.0, g2 = 0.0;
  for (int t = 0; t < T; t++) {
    double s = d5[(size_t)(b * T + t) * 410 + o];
    g1 = s + A1 * g1;
    g2 = g1 + A1 * g2;
    s5[(size_t)(b * T + t) * 410 + o] = (CE * (g2 - g1) >= 1.0) ? 1 : 0;
  }
}

// Stage 6a: dense2 matmul.  One thread per (bt,o).
__global__ void k_dense2(const unsigned char* __restrict__ s5, const float* __restrict__ wf2,
                         double* __restrict__ d6) {
  int tid = blockIdx.x * 256 + threadIdx.x;
  if (tid >= B * T * 10) return;
  int o = tid % 10, bt = tid / 10;
  const unsigned char* sr = s5 + (size_t)bt * 410;
  const float* wr = wf2 + o * 410;
  double s = 0.0;
  for (int i = 0; i < 410; i++) s += (double)wr[i] * (double)sr[i];
  d6[tid] = s;
}

// Stage 6b: final psp + spike -> d_out [b][o][t] f32.
__global__ void k_psp6(const double* __restrict__ d6, float* __restrict__ out) {
  int tid = blockIdx.x * 256 + threadIdx.x;
  if (tid >= B * 10) return;
  int o = tid % 10, b = tid / 10;
  double g1 = 0.0, g2 = 0.0;
  for (int t = 0; t < T; t++) {
    double s = d6[(size_t)(b * T + t) * 10 + o];
    g1 = s + A1 * g1;
    g2 = g1 + A1 * g2;
    out[(size_t)b * 1000 + o * 100 + t] = (CE * (g2 - g1) >= 1.0) ? 1.0f : 0.0f;
  }
}

extern "C" void kernel_launch(void* const* d_in, const int* in_sizes, int n_in,
                              void* d_out, int out_size, void* d_ws, size_t ws_size,
                              hipStream_t stream) {
  const float* img = (const float*)d_in[0];
  const float* ru = (const float*)d_in[1];
  const float* w1 = (const float*)d_in[2];
  const float* w2 = (const float*)d_in[3];
  const float* wf1 = (const float*)d_in[4];
  const float* wf2 = (const float*)d_in[5];

  unsigned char* ws = (unsigned char*)d_ws;
  unsigned char* x0 = ws + OFF_X0;
  unsigned char* s1 = ws + OFF_S1;
  unsigned char* s2 = ws + OFF_S2;
  unsigned char* s3 = ws + OFF_S3;
  unsigned char* s4 = ws + OFF_S4;
  double* d5 = (double*)(ws + OFF_D5);
  unsigned char* s5 = ws + OFF_S5;
  double* d6 = (double*)(ws + OFF_D6);
  float* wt = (float*)(ws + OFF_WT);
  float* out = (float*)d_out;

  k_encode<<<(B * T * 784 + 255) / 256, 256, 0, stream>>>(img, ru, x0);
  k_transpose<<<(410 * 1568 + 255) / 256, 256, 0, stream>>>(wf1, wt);
  k_conv1<<<(B * 16 * 784 + 255) / 256, 256, 0, stream>>>(x0, w1, s1);
  k_pool<16, 14, 14><<<(B * 16 * 196 + 255) / 256, 256, 0, stream>>>(s1, s2);
  k_conv2<<<dim3(B * 32), 256, 0, stream>>>(s2, w2, s3);
  k_pool<32, 7, 7><<<(B * 32 * 49 + 255) / 256, 256, 0, stream>>>(s3, s4);
  k_dense1<<<dim3(7, 200), 256, 0, stream>>>(s4, wt, d5);
  k_psp5<<<(B * 410 + 255) / 256, 256, 0, stream>>>(d5, s5);
  k_dense2<<<(B * T * 10 + 255) / 256, 256, 0, stream>>>(s5, wf2, d6);
  k_psp6<<<2, 256, 0, stream>>>(d6, out);
}

// Round 2
// 685.383 us; speedup vs baseline: 4.1841x; 4.1841x over previous
//
#include <hip/hip_runtime.h>

// ---------------------------------------------------------------------------
// SLAYER-style spiking CNN forward pass, MI355X.  Round 2.
//
// psp (SRM alpha kernel) as double-exponential IIR cascade (exact):
//   eps[k] = (e/tau)*k*a^k, a = exp(-1/tau)
//   g1[t] = x[t] + a*g1[t-1]; g2[t] = g1[t] + a*g2[t-1]; u = (e/tau)*(g2-g1)
//
// R2: binary spikes -> bitmask rows + 32-entry f64 LUT per (ci,dy) replaces
// per-tap LDS byte reads (LDS-issue bound in R1).  Pool+IIR fused into the
// conv blocks; standalone pool kernels and s1/s3 tensors eliminated.
// All accumulation in f64 for exact spike-pattern match.
// ---------------------------------------------------------------------------

namespace {
constexpr int B = 32, T = 100;
constexpr double A1 = 0.90483741803595957;  // exp(-1/10)
constexpr double CE = 0.27182818284590452;  // e/10

// workspace byte offsets
constexpr size_t OFF_M1 = 0;                                  // u32 [B*T][28]
constexpr size_t OFF_M2 = OFF_M1 + (size_t)B * T * 28 * 4;    // u32 [B*T][16][14]
constexpr size_t OFF_S4 = OFF_M2 + (size_t)B * T * 224 * 4;   // u8  [B*T][1568]
constexpr size_t OFF_D5 = OFF_S4 + (size_t)B * T * 1568;      // f64 [B*T][410]
constexpr size_t OFF_S5 = OFF_D5 + (size_t)B * T * 410 * 8;   // u8  [B*T][410]
constexpr size_t OFF_D6 = OFF_S5 + (size_t)B * T * 410;       // f64 [B*T][10]
constexpr size_t OFF_WT = OFF_D6 + (size_t)B * T * 10 * 8;    // f32 [1568][410]
}  // namespace

// Stage 0: rate encode + bit-pack rows.  Thread per (b,y,t); loops x.
// m1[(b*T+t)*28 + y] bit x = (ru[b,y,x,t] < img[b,y,x])
__global__ void k_encode_pack(const float* __restrict__ img, const float* __restrict__ ru,
                              unsigned int* __restrict__ m1) {
  int i = blockIdx.x * 256 + threadIdx.x;
  if (i >= B * 28 * T) return;
  int t = i % T;
  int y = (i / T) % 28;
  int b = i / (T * 28);
  unsigned int m = 0;
  const float* rb = ru + ((size_t)b * 784 + y * 28) * T + t;
  const float* ib = img + b * 784 + y * 28;
  for (int x = 0; x < 28; x++) {
    m |= (rb[(size_t)x * T] < ib[x]) ? (1u << x) : 0u;
  }
  m1[((size_t)b * T + t) * 28 + y] = m;
}

// Stage 1 fused: conv1 (1->16,5x5,pad2) + psp + spike + pool2 + psp + spike.
// Block = (b,o); outputs conv2-input row masks m2[bt][o][14].
__global__ __launch_bounds__(256) void k_conv1(const unsigned int* __restrict__ m1,
                                               const float* __restrict__ w1,
                                               unsigned int* __restrict__ m2) {
  __shared__ double lut[160];        // [dy][32]
  __shared__ unsigned int mrow[32];  // rows iy=-2..29 at idx iy+2; guards 0
  __shared__ unsigned char spk[784];
  __shared__ unsigned char spkP[196];
  int o = blockIdx.x % 16, b = blockIdx.x / 16;
  int tid = threadIdx.x;
  if (tid < 160) {
    int dy = tid / 32, f = tid % 32;
    double v = 0.0;
    const float* wb = w1 + o * 25 + dy * 5;
#pragma unroll
    for (int dx = 0; dx < 5; dx++)
      if ((f >> dx) & 1) v += (double)wb[dx];
    lut[tid] = v;
  }
  if (tid < 32) mrow[tid] = 0;  // guards (0,1,30,31) stay 0 forever
  int y = tid / 7, xg = tid % 7;  // conv coords: 28 rows x 7 groups of 4 px
  int py = tid / 14, px = tid % 14;  // pooled coords
  bool act = tid < 196;
  double g1[4] = {0, 0, 0, 0}, g2[4] = {0, 0, 0, 0};
  double p1 = 0.0, p2 = 0.0;
  const unsigned int* m1b = m1 + (size_t)b * T * 28;
  for (int t = 0; t < T; t++) {
    __syncthreads();
    if (tid < 28) mrow[tid + 2] = m1b[t * 28 + tid] << 2;  // pre-shifted
    __syncthreads();
    if (act) {
      double s0 = 0, s1 = 0, s2 = 0, s3 = 0;
      int xb = xg * 4;
#pragma unroll
      for (int dy = 0; dy < 5; dy++) {
        unsigned int m = mrow[y + dy];
        const double* ld = lut + dy * 32;
        s0 += ld[(m >> (xb + 0)) & 31];
        s1 += ld[(m >> (xb + 1)) & 31];
        s2 += ld[(m >> (xb + 2)) & 31];
        s3 += ld[(m >> (xb + 3)) & 31];
      }
      g1[0] = s0 + A1 * g1[0]; g2[0] = g1[0] + A1 * g2[0];
      g1[1] = s1 + A1 * g1[1]; g2[1] = g1[1] + A1 * g2[1];
      g1[2] = s2 + A1 * g1[2]; g2[2] = g1[2] + A1 * g2[2];
      g1[3] = s3 + A1 * g1[3]; g2[3] = g1[3] + A1 * g2[3];
      unsigned char* sp = spk + y * 28 + xb;
      sp[0] = (CE * (g2[0] - g1[0]) >= 1.0) ? 1 : 0;
      sp[1] = (CE * (g2[1] - g1[1]) >= 1.0) ? 1 : 0;
      sp[2] = (CE * (g2[2] - g1[2]) >= 1.0) ? 1 : 0;
      sp[3] = (CE * (g2[3] - g1[3]) >= 1.0) ? 1 : 0;
    }
    __syncthreads();
    if (act) {
      const unsigned char* r0 = spk + (2 * py) * 28 + 2 * px;
      int sum = (int)r0[0] + (int)r0[1] + (int)r0[28] + (int)r0[29];
      double s = 1.1 * (double)sum;
      p1 = s + A1 * p1;
      p2 = p1 + A1 * p2;
      spkP[tid] = (CE * (p2 - p1) >= 1.0) ? 1 : 0;
    }
    __syncthreads();
    if (tid < 14) {
      unsigned int m = 0;
      const unsigned char* rp = spkP + tid * 14;
#pragma unroll
      for (int xx = 0; xx < 14; xx++) m |= ((unsigned int)rp[xx]) << xx;
      m2[((size_t)(b * T + t) * 16 + o) * 14 + tid] = m;
    }
  }
}

// Stage 3 fused: conv2 (16->32,5x5,pad2) + psp + spike + pool2 + psp + spike.
// Block = (b,o); outputs dense1-input bytes s4[bt][o*49 + p].
__global__ __launch_bounds__(256) void k_conv2(const unsigned int* __restrict__ m2,
                                               const float* __restrict__ w2,
                                               unsigned char* __restrict__ s4) {
  __shared__ double lut[2560];         // [ci][dy][32]  (20480 B)
  __shared__ unsigned int mrow2[288];  // [row 0..17][ci 0..15]; guard rows 0,1,16,17
  __shared__ unsigned char spk[196];
  int o = blockIdx.x % 32, b = blockIdx.x / 32;
  int tid = threadIdx.x;
  for (int e = tid; e < 2560; e += 256) {
    int ci = e / 160, rr = e % 160, dy = rr / 32, f = rr % 32;
    double v = 0.0;
    const float* wb = w2 + o * 400 + ci * 25 + dy * 5;
#pragma unroll
    for (int dx = 0; dx < 5; dx++)
      if ((f >> dx) & 1) v += (double)wb[dx];
    lut[e] = v;  // e == (ci*5+dy)*32 + f
  }
  for (int k = tid; k < 288; k += 256) mrow2[k] = 0;
  int y = tid / 14, x = tid % 14;
  int py = tid / 7, px = tid % 7;
  bool act = tid < 196;
  double g1 = 0.0, g2 = 0.0, p1 = 0.0, p2 = 0.0;
  const unsigned int* m2b = m2 + (size_t)b * T * 224;
  for (int t = 0; t < T; t++) {
    __syncthreads();
    if (tid < 224) {
      int ci = tid / 14, r = tid % 14;
      mrow2[(r + 2) * 16 + ci] = m2b[(size_t)t * 224 + tid] << 2;  // pre-shifted
    }
    __syncthreads();
    if (act) {
      double s = 0.0;
#pragma unroll
      for (int dy = 0; dy < 5; dy++) {
        const uint4* q = (const uint4*)(mrow2 + (y + dy) * 16);
        uint4 qa = q[0], qb = q[1], qc = q[2], qd = q[3];
        const double* ld = lut + dy * 32;
        s += ld[0 * 160 + ((qa.x >> x) & 31)];
        s += ld[1 * 160 + ((qa.y >> x) & 31)];
        s += ld[2 * 160 + ((qa.z >> x) & 31)];
        s += ld[3 * 160 + ((qa.w >> x) & 31)];
        s += ld[4 * 160 + ((qb.x >> x) & 31)];
        s += ld[5 * 160 + ((qb.y >> x) & 31)];
        s += ld[6 * 160 + ((qb.z >> x) & 31)];
        s += ld[7 * 160 + ((qb.w >> x) & 31)];
        s += ld[8 * 160 + ((qc.x >> x) & 31)];
        s += ld[9 * 160 + ((qc.y >> x) & 31)];
        s += ld[10 * 160 + ((qc.z >> x) & 31)];
        s += ld[11 * 160 + ((qc.w >> x) & 31)];
        s += ld[12 * 160 + ((qd.x >> x) & 31)];
        s += ld[13 * 160 + ((qd.y >> x) & 31)];
        s += ld[14 * 160 + ((qd.z >> x) & 31)];
        s += ld[15 * 160 + ((qd.w >> x) & 31)];
      }
      g1 = s + A1 * g1;
      g2 = g1 + A1 * g2;
      spk[tid] = (CE * (g2 - g1) >= 1.0) ? 1 : 0;
    }
    __syncthreads();
    if (tid < 49) {
      const unsigned char* r0 = spk + (2 * py) * 14 + 2 * px;
      int sum = (int)r0[0] + (int)r0[1] + (int)r0[14] + (int)r0[15];
      double s = 1.1 * (double)sum;
      p1 = s + A1 * p1;
      p2 = p1 + A1 * p2;
      s4[(size_t)(b * T + t) * 1568 + o * 49 + tid] = (CE * (p2 - p1) >= 1.0) ? 1 : 0;
    }
  }
}

// Transpose wf1 [410][1568] -> wt [1568][410] for coalesced dense1 reads.
__global__ void k_transpose(const float* __restrict__ wf1, float* __restrict__ wt) {
  int i = blockIdx.x * 256 + threadIdx.x;
  if (i >= 410 * 1568) return;
  int col = i % 410, row = i / 410;
  wt[i] = wf1[col * 1568 + row];
}

// Stage 5a: dense1 matmul.  Block = 64 o-lanes x 4 bt-groups; 16 (b,t) columns in LDS.
__global__ __launch_bounds__(256) void k_dense1(const unsigned char* __restrict__ s4,
                                                const float* __restrict__ wt,
                                                double* __restrict__ d5) {
  __shared__ unsigned char sl[16 * 1568];  // 25088 B
  int obase = blockIdx.x * 64;   // gridDim.x = 7
  int btbase = blockIdx.y * 16;  // gridDim.y = 200
  int tid = threadIdx.x;
  int olane = tid % 64, bts = tid / 64;
  const unsigned int* src = (const unsigned int*)(s4 + (size_t)btbase * 1568);
  unsigned int* dst = (unsigned int*)sl;
  for (int k = tid; k < 6272; k += 256) dst[k] = src[k];
  __syncthreads();
  int o = obase + olane;
  bool store = o < 410;
  int osafe = store ? o : 409;
  double a0 = 0.0, a1 = 0.0, a2 = 0.0, a3 = 0.0;
  const unsigned char* c0 = sl + (bts * 4 + 0) * 1568;
  const unsigned char* c1 = sl + (bts * 4 + 1) * 1568;
  const unsigned char* c2 = sl + (bts * 4 + 2) * 1568;
  const unsigned char* c3 = sl + (bts * 4 + 3) * 1568;
  for (int i = 0; i < 1568; i++) {
    double wv = (double)wt[(size_t)i * 410 + osafe];
    a0 += wv * (double)c0[i];
    a1 += wv * (double)c1[i];
    a2 += wv * (double)c2[i];
    a3 += wv * (double)c3[i];
  }
  if (store) {
    d5[(size_t)(btbase + bts * 4 + 0) * 410 + o] = a0;
    d5[(size_t)(btbase + bts * 4 + 1) * 410 + o] = a1;
    d5[(size_t)(btbase + bts * 4 + 2) * 410 + o] = a2;
    d5[(size_t)(btbase + bts * 4 + 3) * 410 + o] = a3;
  }
}

// Stage 5b: psp + spike over dense1 output.  One thread per (b,o).
__global__ void k_psp5(const double* __restrict__ d5, unsigned char* __restrict__ s5) {
  int tid = blockIdx.x * 256 + threadIdx.x;
  if (tid >= B * 410) return;
  int o = tid % 410, b = tid / 410;
  double g1 = 0.0, g2 = 0.0;
  for (int t = 0; t < T; t++) {
    double s = d5[(size_t)(b * T + t) * 410 + o];
    g1 = s + A1 * g1;
    g2 = g1 + A1 * g2;
    s5[(size_t)(b * T + t) * 410 + o] = (CE * (g2 - g1) >= 1.0) ? 1 : 0;
  }
}

// Stage 6a: dense2 matmul.  One thread per (bt,o).
__global__ void k_dense2(const unsigned char* __restrict__ s5, const float* __restrict__ wf2,
                         double* __restrict__ d6) {
  int tid = blockIdx.x * 256 + threadIdx.x;
  if (tid >= B * T * 10) return;
  int o = tid % 10, bt = tid / 10;
  const unsigned char* sr = s5 + (size_t)bt * 410;
  const float* wr = wf2 + o * 410;
  double s = 0.0;
  for (int i = 0; i < 410; i++) s += (double)wr[i] * (double)sr[i];
  d6[tid] = s;
}

// Stage 6b: final psp + spike -> d_out [b][o][t] f32.
__global__ void k_psp6(const double* __restrict__ d6, float* __restrict__ out) {
  int tid = blockIdx.x * 256 + threadIdx.x;
  if (tid >= B * 10) return;
  int o = tid % 10, b = tid / 10;
  double g1 = 0.0, g2 = 0.0;
  for (int t = 0; t < T; t++) {
    double s = d6[(size_t)(b * T + t) * 10 + o];
    g1 = s + A1 * g1;
    g2 = g1 + A1 * g2;
    out[(size_t)b * 1000 + o * 100 + t] = (CE * (g2 - g1) >= 1.0) ? 1.0f : 0.0f;
  }
}

extern "C" void kernel_launch(void* const* d_in, const int* in_sizes, int n_in,
                              void* d_out, int out_size, void* d_ws, size_t ws_size,
                              hipStream_t stream) {
  const float* img = (const float*)d_in[0];
  const float* ru = (const float*)d_in[1];
  const float* w1 = (const float*)d_in[2];
  const float* w2 = (const float*)d_in[3];
  const float* wf1 = (const float*)d_in[4];
  const float* wf2 = (const float*)d_in[5];

  unsigned char* ws = (unsigned char*)d_ws;
  unsigned int* m1 = (unsigned int*)(ws + OFF_M1);
  unsigned int* m2 = (unsigned int*)(ws + OFF_M2);
  unsigned char* s4 = ws + OFF_S4;
  double* d5 = (double*)(ws + OFF_D5);
  unsigned char* s5 = ws + OFF_S5;
  double* d6 = (double*)(ws + OFF_D6);
  float* wt = (float*)(ws + OFF_WT);
  float* out = (float*)d_out;

  k_encode_pack<<<(B * 28 * T + 255) / 256, 256, 0, stream>>>(img, ru, m1);
  k_transpose<<<(410 * 1568 + 255) / 256, 256, 0, stream>>>(wf1, wt);
  k_conv1<<<B * 16, 256, 0, stream>>>(m1, w1, m2);
  k_conv2<<<B * 32, 256, 0, stream>>>(m2, w2, s4);
  k_dense1<<<dim3(7, 200), 256, 0, stream>>>(s4, wt, d5);
  k_psp5<<<(B * 410 + 255) / 256, 256, 0, stream>>>(d5, s5);
  k_dense2<<<(B * T * 10 + 255) / 256, 256, 0, stream>>>(s5, wf2, d6);
  k_psp6<<<2, 256, 0, stream>>>(d6, out);
}